// Round 1
// baseline (26.169 us; speedup 1.0000x reference)
//
#include <hip/hip_runtime.h>

// E[b] = sum_n h_n^T (0.5*I + 0.1*W) h_n  — pure streaming reduction.
// B=64 batches, N=65536 nodes, I=8 blades. h: (B,N,I) f32 contiguous, W: (8,8) f32.

#define B_ 64
#define N_ 65536
#define I_ 8
#define BLOCKS_PER_BATCH 32
#define THREADS 256
#define NODES_PER_BLOCK (N_ / BLOCKS_PER_BATCH)      // 2048
#define NODES_PER_THREAD (NODES_PER_BLOCK / THREADS) // 8

__global__ __launch_bounds__(THREADS) void energy_partial_kernel(
    const float* __restrict__ h, const float* __restrict__ W,
    float* __restrict__ partial) {
  const int blk = blockIdx.x;
  const int b = blk / BLOCKS_PER_BATCH;
  const int chunk = blk % BLOCKS_PER_BATCH;
  const int t = threadIdx.x;

  // M = 0.5*I + 0.1*W. Uniform address -> s_load; FMAs get SGPR operands.
  float M[I_][I_];
#pragma unroll
  for (int i = 0; i < I_; ++i)
#pragma unroll
    for (int j = 0; j < I_; ++j)
      M[i][j] = 0.1f * W[i * I_ + j] + (i == j ? 0.5f : 0.0f);

  const size_t base = (size_t)b * N_ + (size_t)chunk * NODES_PER_BLOCK;
  float acc = 0.0f;

#pragma unroll
  for (int k = 0; k < NODES_PER_THREAD; ++k) {
    const size_t node = base + (size_t)k * THREADS + (size_t)t;
    const float4* p = reinterpret_cast<const float4*>(h + node * I_);
    float4 a = p[0];
    float4 c = p[1];
    float hv[I_] = {a.x, a.y, a.z, a.w, c.x, c.y, c.z, c.w};
    float e = 0.0f;
#pragma unroll
    for (int i = 0; i < I_; ++i) {
      float ti = 0.0f;
#pragma unroll
      for (int j = 0; j < I_; ++j) ti = fmaf(M[i][j], hv[j], ti);
      e = fmaf(hv[i], ti, e);
    }
    acc += e;
  }

  // Wave(64)-wide shuffle reduction, then cross-wave via LDS.
#pragma unroll
  for (int off = 32; off > 0; off >>= 1)
    acc += __shfl_down(acc, off, 64);

  __shared__ float wsum[THREADS / 64];
  const int wave = t >> 6;
  const int lane = t & 63;
  if (lane == 0) wsum[wave] = acc;
  __syncthreads();
  if (t == 0) {
    float s = 0.0f;
#pragma unroll
    for (int w = 0; w < THREADS / 64; ++w) s += wsum[w];
    partial[blk] = s;
  }
}

__global__ void energy_final_kernel(const float* __restrict__ partial,
                                    float* __restrict__ out) {
  const int b = threadIdx.x;
  if (b < B_) {
    float s = 0.0f;
#pragma unroll
    for (int c = 0; c < BLOCKS_PER_BATCH; ++c)
      s += partial[(size_t)b * BLOCKS_PER_BATCH + c];
    out[b] = s;
  }
}

extern "C" void kernel_launch(void* const* d_in, const int* in_sizes, int n_in,
                              void* d_out, int out_size, void* d_ws, size_t ws_size,
                              hipStream_t stream) {
  const float* h = (const float*)d_in[0];
  const float* W = (const float*)d_in[1];
  float* partial = (float*)d_ws;     // B_*BLOCKS_PER_BATCH = 2048 floats
  float* out = (float*)d_out;

  energy_partial_kernel<<<B_ * BLOCKS_PER_BATCH, THREADS, 0, stream>>>(h, W, partial);
  energy_final_kernel<<<1, 64, 0, stream>>>(partial, out);
}